// Round 1
// baseline (3824.592 us; speedup 1.0000x reference)
//
#include <hip/hip_runtime.h>
#include <hip/hip_bf16.h>

// ---------------------------------------------------------------------------
// LiquidPerceptionUnit: CNN encoder (per-timestep) + 3-layer WiredCfC scan.
// B=32, T=512, L=256, FEAT=128; layers (fin,hid): (128,116),(116,76),(76,64)
//
// Strategy:
//   K0 prep   : fold mask into w1/w2, fold wa+wb, transpose+pack weights
//               (k-major, 4-k packed for float4 loads), transpose fc_w.
//   K1 encode : one block per sample -> feats[16384][128]
//   K2 proj   : feats @ L0-input-weights (+bias) for ALL t in parallel
//               -> proj0[16384][348]   (348 = 3 mats x 116)
//   K3 recur  : 32 blocks (one per batch), 512 serial steps, weights
//               streamed from L2 (all blocks share the same arrays).
// ---------------------------------------------------------------------------

#define BB 32
#define TT 512

struct Ptrs { const float* p[34]; };

// input indices (setup_inputs dict order):
// 0:x 1:c1_w 2:c1_b 3:c2_w 4:c2_b 5:fc_w 6:fc_b
// 7:l0_mask 8:l0_w1 9:l0_w2 10:l0_wa 11:l0_wb 12:l0_b1 13:l0_b2 14:l0_ba 15:l0_bb
// 16:l1_mask 17:l1_w1 18:l1_w2 19:l1_wa 20:l1_wb 21:l1_b1 22:l1_b2 23:l1_ba 24:l1_bb
// 25:l2_mask 26:l2_w1 27:l2_w2 28:l2_wa 29:l2_wb 30:l2_b1 31:l2_b2 32:l2_ba 33:l2_bb

__device__ __forceinline__ float wv(const float* w1, const float* w2,
                                    const float* wa, const float* wb,
                                    const float* msk, int m, int o, int col, int cat) {
  int idx = o * cat + col;
  if (m == 0) return w1[idx] * msk[idx];
  if (m == 1) return w2[idx] * msk[idx];
  return wa[idx] + wb[idx];
}

// sizes of prep regions (floats)
#define SZ_FCWT  16384            // [32][128][4]  (kc, f, q) ; k = kc*4+q
#define SZ_M0T   44544            // [32][348][4]  L0 input-proj weights
#define SZ_W0T   40368            // [29][348][4]  L0 recurrent weights
#define SZ_W1T   43776            // [48][228][4]  L1 full-cat weights
#define SZ_W2T   26880            // [35][192][4]  L2 full-cat weights
#define SZ_B1    228
#define SZ_B2    192
#define PREP_TOTAL (SZ_FCWT + SZ_M0T + SZ_W0T + SZ_W1T + SZ_W2T + SZ_B1 + SZ_B2)

__global__ void prep_kernel(Ptrs P, float* __restrict__ fcwTp, float* __restrict__ M0Tp,
                            float* __restrict__ W0Tp, float* __restrict__ W1Tp,
                            float* __restrict__ W2Tp, float* __restrict__ b1f,
                            float* __restrict__ b2f) {
  int i = blockIdx.x * blockDim.x + threadIdx.x;
  if (i < SZ_FCWT) {                    // fc_w transpose+pack: [kc][f][q] = fc_w[f][kc*4+q]
    int kc = i >> 9, r = i & 511, f = r >> 2, q = r & 3;
    fcwTp[i] = P.p[5][f * 128 + (kc * 4 + q)];
    return;
  }
  i -= SZ_FCWT;
  if (i < SZ_M0T) {                     // L0 input part (cols 0..127 of cat=244)
    int kc = i / 1392, r = i % 1392, c = r >> 2, q = r & 3;
    int k = kc * 4 + q, m = c / 116, o = c % 116;
    M0Tp[i] = wv(P.p[8], P.p[9], P.p[10], P.p[11], P.p[7], m, o, k, 244);
    return;
  }
  i -= SZ_M0T;
  if (i < SZ_W0T) {                     // L0 recurrent part (cols 128..243)
    int kc = i / 1392, r = i % 1392, c = r >> 2, q = r & 3;
    int k = kc * 4 + q, m = c / 116, o = c % 116;
    W0Tp[i] = wv(P.p[8], P.p[9], P.p[10], P.p[11], P.p[7], m, o, 128 + k, 244);
    return;
  }
  i -= SZ_W0T;
  if (i < SZ_W1T) {                     // L1 full cat=192
    int kc = i / 912, r = i % 912, c = r >> 2, q = r & 3;
    int k = kc * 4 + q, m = c / 76, o = c % 76;
    W1Tp[i] = wv(P.p[17], P.p[18], P.p[19], P.p[20], P.p[16], m, o, k, 192);
    return;
  }
  i -= SZ_W1T;
  if (i < SZ_W2T) {                     // L2 full cat=140
    int kc = i / 768, r = i % 768, c = r >> 2, q = r & 3;
    int k = kc * 4 + q, m = c / 64, o = c % 64;
    W2Tp[i] = wv(P.p[26], P.p[27], P.p[28], P.p[29], P.p[25], m, o, k, 140);
    return;
  }
  i -= SZ_W2T;
  if (i < SZ_B1) {
    int m = i / 76, o = i % 76;
    b1f[i] = (m == 0) ? P.p[21][o] : (m == 1) ? P.p[22][o] : (P.p[23][o] + P.p[24][o]);
    return;
  }
  i -= SZ_B1;
  if (i < SZ_B2) {
    int m = i / 64, o = i % 64;
    b2f[i] = (m == 0) ? P.p[30][o] : (m == 1) ? P.p[31][o] : (P.p[32][o] + P.p[33][o]);
    return;
  }
}

// ---------------------------------------------------------------------------
// Encoder: one block (128 threads) per sample.
__global__ __launch_bounds__(128) void encoder_kernel(
    const float* __restrict__ x, const float* __restrict__ c1w,
    const float* __restrict__ c1b, const float* __restrict__ c2w,
    const float* __restrict__ c2b, const float* __restrict__ fcwTp,
    const float* __restrict__ fcb, float* __restrict__ feats) {
  __shared__ __align__(16) float xsh[258];      // halo-padded input row
  __shared__ float pooled[128];                 // [p(8)][c(16)]
  __shared__ __align__(16) float vflat[128];    // [c(32)*4 + p4]
  const int n = blockIdx.x, tid = threadIdx.x;
  const float* xr = x + n * 256;
  xsh[1 + tid] = xr[tid];
  xsh[129 + tid] = xr[128 + tid];
  if (tid == 0) { xsh[0] = 0.f; xsh[257] = 0.f; }
  __syncthreads();
  {                                             // conv1 + relu + avgpool(32)
    int c = tid & 15, p = tid >> 4;
    float w0 = c1w[c * 3], w1 = c1w[c * 3 + 1], w2 = c1w[c * 3 + 2], b = c1b[c];
    float s = 0.f;
    int base = p * 32;
    #pragma unroll 8
    for (int j = 0; j < 32; ++j) {
      float v = b + w0 * xsh[base + j] + w1 * xsh[base + j + 1] + w2 * xsh[base + j + 2];
      s += fmaxf(v, 0.f);
    }
    pooled[p * 16 + c] = s * (1.f / 32.f);
  }
  __syncthreads();
  {                                             // conv2 + relu + avgpool(2)
    int c = tid & 31, p4 = tid >> 5;
    float s = 0.f;
    for (int pp = 0; pp < 2; ++pp) {
      int p = p4 * 2 + pp;
      float v = c2b[c];
      #pragma unroll
      for (int ci = 0; ci < 16; ++ci) {
        #pragma unroll
        for (int j = 0; j < 3; ++j) {
          int q = p + j - 1;
          float pv = (q >= 0 && q < 8) ? pooled[q * 16 + ci] : 0.f;
          v = fmaf(c2w[(c * 16 + ci) * 3 + j], pv, v);
        }
      }
      s += fmaxf(v, 0.f);
    }
    vflat[c * 4 + p4] = s * 0.5f;
  }
  __syncthreads();
  {                                             // FC 128x128
    const float4* W = (const float4*)fcwTp;
    const float4* vv = (const float4*)vflat;
    float a0 = 0, a1 = 0, a2 = 0, a3 = 0;
    #pragma unroll 8
    for (int kc = 0; kc < 32; ++kc) {
      float4 w = W[kc * 128 + tid];
      float4 h = vv[kc];
      a0 = fmaf(w.x, h.x, a0); a1 = fmaf(w.y, h.y, a1);
      a2 = fmaf(w.z, h.z, a2); a3 = fmaf(w.w, h.w, a3);
    }
    feats[n * 128 + tid] = fcb[tid] + ((a0 + a1) + (a2 + a3));
  }
}

// ---------------------------------------------------------------------------
// L0 input projection for all (b,t): proj0[n][c] = bias0[c] + feats[n] . M0[c]
__global__ __launch_bounds__(256) void proj_kernel(
    const float* __restrict__ feats, const float* __restrict__ M0Tp,
    const float* __restrict__ b01, const float* __restrict__ b02,
    const float* __restrict__ b0a, const float* __restrict__ b0b,
    float* __restrict__ proj0) {
  __shared__ __align__(16) float fl[32 * 128];
  const int tid = threadIdx.x;
  const int n0 = blockIdx.x * 32;
  const float4* src = (const float4*)(feats + n0 * 128);
  float4* dst4 = (float4*)fl;
  for (int i = tid; i < 32 * 32; i += 256) dst4[i] = src[i];
  __syncthreads();
  const float4* W = (const float4*)M0Tp;
  for (int i = tid; i < 32 * 348; i += 256) {
    int s = i / 348, c = i - s * 348;
    int m = c / 116, o = c - m * 116;
    float acc = (m == 0) ? b01[o] : (m == 1) ? b02[o] : (b0a[o] + b0b[o]);
    const float4* hv = (const float4*)(fl + s * 128);
    float a0 = 0, a1 = 0, a2 = 0, a3 = 0;
    #pragma unroll 8
    for (int kc = 0; kc < 32; ++kc) {
      float4 w = W[kc * 348 + c];
      float4 h = hv[kc];
      a0 = fmaf(w.x, h.x, a0); a1 = fmaf(w.y, h.y, a1);
      a2 = fmaf(w.z, h.z, a2); a3 = fmaf(w.w, h.w, a3);
    }
    proj0[(n0 + s) * 348 + c] = acc + ((a0 + a1) + (a2 + a3));
  }
}

// ---------------------------------------------------------------------------
// Recurrent scan: one block per batch element, 512 serial steps.
__global__ __launch_bounds__(384) void recurrent_kernel(
    const float* __restrict__ proj0, const float* __restrict__ W0Tp,
    const float* __restrict__ W1Tp, const float* __restrict__ W2Tp,
    const float* __restrict__ b1f, const float* __restrict__ b2f,
    float* __restrict__ dout) {
  __shared__ __align__(16) float xx1[192];   // [h0(116) | h1(76)]
  __shared__ __align__(16) float xx2[140];   // [h1(76)  | h2(64)]
  __shared__ float pre0[348], pre1[228], pre2[192];
  __shared__ float b1s[228], b2s[192];
  const int tid = threadIdx.x, b = blockIdx.x;
  for (int i = tid; i < 192; i += 384) xx1[i] = 0.f;
  for (int i = tid; i < 140; i += 384) xx2[i] = 0.f;
  for (int i = tid; i < 228; i += 384) b1s[i] = b1f[i];
  for (int i = tid; i < 192; i += 384) b2s[i] = b2f[i];
  __syncthreads();
  const float4* W0 = (const float4*)W0Tp;
  const float4* W1 = (const float4*)W1Tp;
  const float4* W2 = (const float4*)W2Tp;
  const float4* x1v = (const float4*)xx1;
  const float4* x2v = (const float4*)xx2;
  float* outp = dout + b * TT * 64;
  const float* pr = proj0 + b * TT * 348;

  for (int t = 0; t < TT; ++t) {
    // ---- L0 recurrent dots (3 mats x 116 outputs, K=116)
    if (tid < 348) {
      float a0 = 0, a1 = 0, a2 = 0, a3 = 0;
      #pragma unroll
      for (int kc = 0; kc < 29; ++kc) {
        float4 w = W0[kc * 348 + tid];
        float4 h = x1v[kc];
        a0 = fmaf(w.x, h.x, a0); a1 = fmaf(w.y, h.y, a1);
        a2 = fmaf(w.z, h.z, a2); a3 = fmaf(w.w, h.w, a3);
      }
      pre0[tid] = pr[t * 348 + tid] + ((a0 + a1) + (a2 + a3));
    }
    __syncthreads();
    // ---- L0 combine
    if (tid < 116) {
      float ti = 1.f / (1.f + expf(-pre0[232 + tid]));
      float f1 = tanhf(pre0[tid]), f2 = tanhf(pre0[116 + tid]);
      xx1[tid] = f1 + ti * (f2 - f1);
    }
    __syncthreads();
    // ---- L1 dots (3 x 76 outputs, K=192 over [h0_new | h1])
    if (tid < 228) {
      float a0 = 0, a1 = 0, a2 = 0, a3 = 0;
      #pragma unroll 8
      for (int kc = 0; kc < 48; ++kc) {
        float4 w = W1[kc * 228 + tid];
        float4 h = x1v[kc];
        a0 = fmaf(w.x, h.x, a0); a1 = fmaf(w.y, h.y, a1);
        a2 = fmaf(w.z, h.z, a2); a3 = fmaf(w.w, h.w, a3);
      }
      pre1[tid] = b1s[tid] + ((a0 + a1) + (a2 + a3));
    }
    __syncthreads();
    // ---- L1 combine
    if (tid < 76) {
      float ti = 1.f / (1.f + expf(-pre1[152 + tid]));
      float f1 = tanhf(pre1[tid]), f2 = tanhf(pre1[76 + tid]);
      float h = f1 + ti * (f2 - f1);
      xx1[116 + tid] = h;
      xx2[tid] = h;
    }
    __syncthreads();
    // ---- L2 dots (3 x 64 outputs, K=140 over [h1_new | h2])
    if (tid < 192) {
      float a0 = 0, a1 = 0, a2 = 0, a3 = 0;
      #pragma unroll
      for (int kc = 0; kc < 35; ++kc) {
        float4 w = W2[kc * 192 + tid];
        float4 h = x2v[kc];
        a0 = fmaf(w.x, h.x, a0); a1 = fmaf(w.y, h.y, a1);
        a2 = fmaf(w.z, h.z, a2); a3 = fmaf(w.w, h.w, a3);
      }
      pre2[tid] = b2s[tid] + ((a0 + a1) + (a2 + a3));
    }
    __syncthreads();
    // ---- L2 combine + emit output
    if (tid < 64) {
      float ti = 1.f / (1.f + expf(-pre2[128 + tid]));
      float f1 = tanhf(pre2[tid]), f2 = tanhf(pre2[64 + tid]);
      float h = f1 + ti * (f2 - f1);
      xx2[76 + tid] = h;
      outp[t * 64 + tid] = h;
    }
    __syncthreads();
  }
  // final state: [h0(116) | h1(76) | h2(64)] per batch
  float* st = dout + BB * TT * 64 + b * 256;
  if (tid < 192) st[tid] = xx1[tid];
  else if (tid < 256) st[tid] = xx2[76 + (tid - 192)];
}

// ---------------------------------------------------------------------------
extern "C" void kernel_launch(void* const* d_in, const int* in_sizes, int n_in,
                              void* d_out, int out_size, void* d_ws, size_t ws_size,
                              hipStream_t stream) {
  (void)in_sizes; (void)n_in; (void)out_size; (void)ws_size;
  Ptrs P;
  for (int i = 0; i < 34; ++i) P.p[i] = (const float*)d_in[i];

  float* ws = (float*)d_ws;
  float* feats = ws;                      // 16384*128 = 2097152
  float* proj0 = feats + 2097152;         // 16384*348 = 5701632
  float* fcwTp = proj0 + 5701632;         // 16384
  float* M0Tp  = fcwTp + SZ_FCWT;         // 44544
  float* W0Tp  = M0Tp + SZ_M0T;           // 40368
  float* W1Tp  = W0Tp + SZ_W0T;           // 43776
  float* W2Tp  = W1Tp + SZ_W1T;           // 26880
  float* b1f   = W2Tp + SZ_W2T;           // 228
  float* b2f   = b1f + SZ_B1;             // 192

  prep_kernel<<<(PREP_TOTAL + 255) / 256, 256, 0, stream>>>(P, fcwTp, M0Tp, W0Tp,
                                                            W1Tp, W2Tp, b1f, b2f);
  encoder_kernel<<<BB * TT, 128, 0, stream>>>(P.p[0], P.p[1], P.p[2], P.p[3],
                                              P.p[4], fcwTp, P.p[6], feats);
  proj_kernel<<<(BB * TT) / 32, 256, 0, stream>>>(feats, M0Tp, P.p[12], P.p[13],
                                                  P.p[14], P.p[15], proj0);
  recurrent_kernel<<<BB, 384, 0, stream>>>(proj0, W0Tp, W1Tp, W2Tp, b1f, b2f,
                                           (float*)d_out);
}

// Round 2
// 1800.548 us; speedup vs baseline: 2.1241x; 2.1241x over previous
//
#include <hip/hip_runtime.h>
#include <hip/hip_bf16.h>

// ---------------------------------------------------------------------------
// LiquidPerceptionUnit: CNN encoder (per-timestep) + 3-layer WiredCfC scan.
// B=32, T=512, L=256, FEAT=128; layers (fin,hid): (128,116),(116,76),(76,64)
//
//   K0 prep   : fold mask into w1/w2, fold wa+wb, build row-major packed
//               weight rows for register-stationary dots; zero pipe flags.
//   K1 encode : one block per sample -> feats[16384][128]
//   K2 proj   : feats @ L0-input-weights (+all L0 biases) for ALL t
//               -> proj0[16384][348]; W-chunk reused across 32 samples.
//   K3 recur  : 96 blocks = 32 batches x 3 layer-stages, pipelined over t.
//               Weights live in REGISTERS (1 output row / thread).
//               Cross-stage h handoff via agent-scope (sc1) atomics -> L3,
//               512-deep ring buffers (producers never block).
// ---------------------------------------------------------------------------

#define BB 32
#define TT 512

struct Ptrs { const float* p[34]; };

// input indices (setup_inputs dict order):
// 0:x 1:c1_w 2:c1_b 3:c2_w 4:c2_b 5:fc_w 6:fc_b
// 7:l0_mask 8:l0_w1 9:l0_w2 10:l0_wa 11:l0_wb 12:l0_b1 13:l0_b2 14:l0_ba 15:l0_bb
// 16:l1_mask 17:l1_w1 18:l1_w2 19:l1_wa 20:l1_wb 21:l1_b1 22:l1_b2 23:l1_ba 24:l1_bb
// 25:l2_mask 26:l2_w1 27:l2_w2 28:l2_wa 29:l2_wb 30:l2_b1 31:l2_b2 32:l2_ba 33:l2_bb

__device__ __forceinline__ float wv(const float* w1, const float* w2,
                                    const float* wa, const float* wb,
                                    const float* msk, int m, int o, int col, int cat) {
  int idx = o * cat + col;
  if (m == 0) return w1[idx] * msk[idx];
  if (m == 1) return w2[idx] * msk[idx];
  return wa[idx] + wb[idx];
}

// prep regions (floats)
#define SZ_FCWT  16384            // [32][128][4]  fc_w transposed+packed
#define SZ_M0T   44544            // [32][348][4]  L0 input-proj weights (k-major)
#define SZ_W0R   40368            // [348][116]    L0 recurrent rows (row-major)
#define SZ_W1R   43776            // [228][192]    L1 rows
#define SZ_W2R   26880            // [192][140]    L2 rows
#define SZ_B1    228
#define SZ_B2    192
#define SZ_FLAGS 32768            // f0[32*512] + f1[32*512] uints
#define PREP_TOTAL (SZ_FCWT + SZ_M0T + SZ_W0R + SZ_W1R + SZ_W2R + SZ_B1 + SZ_B2 + SZ_FLAGS)

__global__ void prep_kernel(Ptrs P, float* __restrict__ fcwTp, float* __restrict__ M0Tp,
                            float* __restrict__ W0R, float* __restrict__ W1R,
                            float* __restrict__ W2R, float* __restrict__ b1f,
                            float* __restrict__ b2f, unsigned int* __restrict__ flags) {
  int i = blockIdx.x * blockDim.x + threadIdx.x;
  if (i < SZ_FCWT) {                    // fc_w: [kc][f][q] = fc_w[f][kc*4+q]
    int kc = i >> 9, r = i & 511, f = r >> 2, q = r & 3;
    fcwTp[i] = P.p[5][f * 128 + (kc * 4 + q)];
    return;
  }
  i -= SZ_FCWT;
  if (i < SZ_M0T) {                     // L0 input part, k-major (cols 0..127 of cat 244)
    int kc = i / 1392, r = i % 1392, c = r >> 2, q = r & 3;
    int k = kc * 4 + q, m = c / 116, o = c % 116;
    M0Tp[i] = wv(P.p[8], P.p[9], P.p[10], P.p[11], P.p[7], m, o, k, 244);
    return;
  }
  i -= SZ_M0T;
  if (i < SZ_W0R) {                     // L0 recurrent rows: [c][k], col=128+k
    int c = i / 116, k = i % 116;
    W0R[i] = wv(P.p[8], P.p[9], P.p[10], P.p[11], P.p[7], c / 116, c % 116, 128 + k, 244);
    return;
  }
  i -= SZ_W0R;
  if (i < SZ_W1R) {                     // L1 rows: [c][k], cat=192
    int c = i / 192, k = i % 192;
    W1R[i] = wv(P.p[17], P.p[18], P.p[19], P.p[20], P.p[16], c / 76, c % 76, k, 192);
    return;
  }
  i -= SZ_W1R;
  if (i < SZ_W2R) {                     // L2 rows: [c][k], cat=140
    int c = i / 140, k = i % 140;
    W2R[i] = wv(P.p[26], P.p[27], P.p[28], P.p[29], P.p[25], c / 64, c % 64, k, 140);
    return;
  }
  i -= SZ_W2R;
  if (i < SZ_B1) {
    int m = i / 76, o = i % 76;
    b1f[i] = (m == 0) ? P.p[21][o] : (m == 1) ? P.p[22][o] : (P.p[23][o] + P.p[24][o]);
    return;
  }
  i -= SZ_B1;
  if (i < SZ_B2) {
    int m = i / 64, o = i % 64;
    b2f[i] = (m == 0) ? P.p[30][o] : (m == 1) ? P.p[31][o] : (P.p[32][o] + P.p[33][o]);
    return;
  }
  i -= SZ_B2;
  if (i < SZ_FLAGS) flags[i] = 0u;
}

// ---------------------------------------------------------------------------
// Encoder: one block (128 threads) per sample.
__global__ __launch_bounds__(128) void encoder_kernel(
    const float* __restrict__ x, const float* __restrict__ c1w,
    const float* __restrict__ c1b, const float* __restrict__ c2w,
    const float* __restrict__ c2b, const float* __restrict__ fcwTp,
    const float* __restrict__ fcb, float* __restrict__ feats) {
  __shared__ __align__(16) float xsh[258];
  __shared__ float pooled[128];                 // [p(8)][c(16)]
  __shared__ __align__(16) float vflat[128];    // [c(32)*4 + p4]
  const int n = blockIdx.x, tid = threadIdx.x;
  const float* xr = x + n * 256;
  xsh[1 + tid] = xr[tid];
  xsh[129 + tid] = xr[128 + tid];
  if (tid == 0) { xsh[0] = 0.f; xsh[257] = 0.f; }
  __syncthreads();
  {                                             // conv1 + relu + avgpool(32)
    int c = tid & 15, p = tid >> 4;
    float w0 = c1w[c * 3], w1 = c1w[c * 3 + 1], w2 = c1w[c * 3 + 2], b = c1b[c];
    float s = 0.f;
    int base = p * 32;
    #pragma unroll 8
    for (int j = 0; j < 32; ++j) {
      float v = b + w0 * xsh[base + j] + w1 * xsh[base + j + 1] + w2 * xsh[base + j + 2];
      s += fmaxf(v, 0.f);
    }
    pooled[p * 16 + c] = s * (1.f / 32.f);
  }
  __syncthreads();
  {                                             // conv2 + relu + avgpool(2)
    int c = tid & 31, p4 = tid >> 5;
    float s = 0.f;
    for (int pp = 0; pp < 2; ++pp) {
      int p = p4 * 2 + pp;
      float v = c2b[c];
      #pragma unroll
      for (int ci = 0; ci < 16; ++ci) {
        #pragma unroll
        for (int j = 0; j < 3; ++j) {
          int q = p + j - 1;
          float pv = (q >= 0 && q < 8) ? pooled[q * 16 + ci] : 0.f;
          v = fmaf(c2w[(c * 16 + ci) * 3 + j], pv, v);
        }
      }
      s += fmaxf(v, 0.f);
    }
    vflat[c * 4 + p4] = s * 0.5f;
  }
  __syncthreads();
  {                                             // FC 128x128
    const float4* W = (const float4*)fcwTp;
    const float4* vv = (const float4*)vflat;
    float a0 = 0, a1 = 0, a2 = 0, a3 = 0;
    #pragma unroll 8
    for (int kc = 0; kc < 32; ++kc) {
      float4 w = W[kc * 128 + tid];
      float4 h = vv[kc];
      a0 = fmaf(w.x, h.x, a0); a1 = fmaf(w.y, h.y, a1);
      a2 = fmaf(w.z, h.z, a2); a3 = fmaf(w.w, h.w, a3);
    }
    feats[n * 128 + tid] = fcb[tid] + ((a0 + a1) + (a2 + a3));
  }
}

// ---------------------------------------------------------------------------
// L0 input projection: thread c computes output c for 32 samples; each W
// chunk is loaded once and reused across the 32 samples (register acc[32]).
__global__ __launch_bounds__(384) void proj_kernel(
    const float* __restrict__ feats, const float* __restrict__ M0Tp,
    const float* __restrict__ b01, const float* __restrict__ b02,
    const float* __restrict__ b0a, const float* __restrict__ b0b,
    float* __restrict__ proj0) {
  __shared__ __align__(16) float fl[32 * 128];
  const int tid = threadIdx.x;
  const int n0 = blockIdx.x * 32;
  const float4* src = (const float4*)(feats + (size_t)n0 * 128);
  float4* dst4 = (float4*)fl;
  for (int i = tid; i < 1024; i += 384) dst4[i] = src[i];
  __syncthreads();
  if (tid < 348) {
    const int c = tid, m = c / 116, o = c % 116;
    const float bias = (m == 0) ? b01[o] : (m == 1) ? b02[o] : (b0a[o] + b0b[o]);
    float acc[32];
    #pragma unroll
    for (int s = 0; s < 32; ++s) acc[s] = bias;
    const float4* W4 = (const float4*)M0Tp;
    const float4* flv = (const float4*)fl;
    for (int kc = 0; kc < 32; ++kc) {
      const float4 w = W4[kc * 348 + c];
      #pragma unroll
      for (int s = 0; s < 32; ++s) {
        float4 h = flv[s * 32 + kc];
        acc[s] = fmaf(w.x, h.x, fmaf(w.y, h.y, fmaf(w.z, h.z, fmaf(w.w, h.w, acc[s]))));
      }
    }
    float* op = proj0 + (size_t)n0 * 348 + c;
    #pragma unroll
    for (int s = 0; s < 32; ++s) op[s * 348] = acc[s];
  }
}

// ---------------------------------------------------------------------------
__device__ __forceinline__ float cfc_combine(float p1, float p2, float pt) {
  float ti = 1.f / (1.f + expf(-pt));
  float f1 = tanhf(p1), f2 = tanhf(p2);
  return f1 + ti * (f2 - f1);
}

// Pipelined recurrent scan: grid = 32 batches x 3 stages.
// role 0: L0 (self-recurrent, reads proj0, emits h0[t])
// role 1: L1 (consumes h0[t], emits h1[t])
// role 2: L2 (consumes h1[t], emits outputs)
__global__ __launch_bounds__(384, 2) void recurrent_kernel(
    const float* __restrict__ proj0, const float* __restrict__ W0R,
    const float* __restrict__ W1R, const float* __restrict__ W2R,
    const float* __restrict__ b1f, const float* __restrict__ b2f,
    float* __restrict__ h0buf, float* __restrict__ h1buf,
    unsigned int* __restrict__ f0, unsigned int* __restrict__ f1,
    float* __restrict__ dout) {
  __shared__ __align__(16) float xh[192];
  __shared__ float pre[348];
  const int tid = threadIdx.x;
  const int b = blockIdx.x / 3;
  const int role = blockIdx.x % 3;
  float* st = dout + BB * TT * 64 + b * 256;

  if (role == 0) {
    // ---------------- stage 0: L0 ----------------
    float4 w[29];
    {
      const int row = (tid < 348) ? tid : 0;
      const float4* wr = (const float4*)(W0R + row * 116);
      #pragma unroll
      for (int i = 0; i < 29; ++i) w[i] = wr[i];
    }
    for (int i = tid; i < 116; i += 384) xh[i] = 0.f;
    __syncthreads();
    const float4* xv = (const float4*)xh;
    const float* pr = proj0 + (size_t)b * TT * 348;
    float* hb = h0buf + (size_t)b * TT * 128;
    unsigned int* fb = f0 + b * TT;
    float pv = (tid < 348) ? pr[tid] : 0.f;           // prefetch t=0
    for (int t = 0; t < TT; ++t) {
      float pvn = (t < TT - 1 && tid < 348) ? pr[(t + 1) * 348 + tid] : 0.f;
      if (tid < 348) {
        float a0 = 0, a1 = 0, a2 = 0, a3 = 0;
        #pragma unroll
        for (int i = 0; i < 29; ++i) {
          float4 h = xv[i];
          a0 = fmaf(w[i].x, h.x, a0); a1 = fmaf(w[i].y, h.y, a1);
          a2 = fmaf(w[i].z, h.z, a2); a3 = fmaf(w[i].w, h.w, a3);
        }
        pre[tid] = pv + ((a0 + a1) + (a2 + a3));
      }
      pv = pvn;
      __syncthreads();
      if (tid < 116) {
        float h = cfc_combine(pre[tid], pre[116 + tid], pre[232 + tid]);
        xh[tid] = h;
        __hip_atomic_store(&hb[t * 128 + tid], h, __ATOMIC_RELAXED, __HIP_MEMORY_SCOPE_AGENT);
        if (t == TT - 1) st[tid] = h;
      }
      __syncthreads();                               // drains payload stores (vmcnt 0)
      if (tid == 0) {
        asm volatile("" ::: "memory");
        __hip_atomic_store(&fb[t], 1u, __ATOMIC_RELAXED, __HIP_MEMORY_SCOPE_AGENT);
      }
    }
  } else if (role == 1) {
    // ---------------- stage 1: L1 ----------------
    float4 w[48];
    float bias;
    {
      const int row = (tid < 228) ? tid : 0;
      const float4* wr = (const float4*)(W1R + row * 192);
      #pragma unroll
      for (int i = 0; i < 48; ++i) w[i] = wr[i];
      bias = b1f[row];
    }
    for (int i = tid; i < 192; i += 384) xh[i] = 0.f;
    __syncthreads();
    const float4* xv = (const float4*)xh;
    const float* hbr = h0buf + (size_t)b * TT * 128;
    float* hbw = h1buf + (size_t)b * TT * 80;
    const unsigned int* fr = f0 + b * TT;
    unsigned int* fw = f1 + b * TT;
    long g = 0;
    for (int t = 0; t < TT; ++t) {
      if (tid == 0) {
        while (__hip_atomic_load(&fr[t], __ATOMIC_RELAXED, __HIP_MEMORY_SCOPE_AGENT) != 1u) {
          __builtin_amdgcn_s_sleep(1);
          if (++g > (1L << 23)) break;               // deadman: fail visibly, don't hang
        }
        asm volatile("" ::: "memory");
      }
      __syncthreads();
      if (tid < 58) {                                // h0[t]: 116 floats = 58 x 8B (sc1 -> L3)
        unsigned long long v = __hip_atomic_load(
            (const unsigned long long*)(hbr + (size_t)t * 128) + tid,
            __ATOMIC_RELAXED, __HIP_MEMORY_SCOPE_AGENT);
        union { unsigned long long u; float2 f; } cv; cv.u = v;
        ((float2*)xh)[tid] = cv.f;
      }
      __syncthreads();
      if (tid < 228) {
        float a0 = 0, a1 = 0, a2 = 0, a3 = 0;
        #pragma unroll
        for (int i = 0; i < 48; ++i) {
          float4 h = xv[i];
          a0 = fmaf(w[i].x, h.x, a0); a1 = fmaf(w[i].y, h.y, a1);
          a2 = fmaf(w[i].z, h.z, a2); a3 = fmaf(w[i].w, h.w, a3);
        }
        pre[tid] = bias + ((a0 + a1) + (a2 + a3));
      }
      __syncthreads();
      if (tid < 76) {
        float h = cfc_combine(pre[tid], pre[76 + tid], pre[152 + tid]);
        xh[116 + tid] = h;
        __hip_atomic_store(&hbw[t * 80 + tid], h, __ATOMIC_RELAXED, __HIP_MEMORY_SCOPE_AGENT);
        if (t == TT - 1) st[116 + tid] = h;
      }
      __syncthreads();
      if (tid == 0) {
        asm volatile("" ::: "memory");
        __hip_atomic_store(&fw[t], 1u, __ATOMIC_RELAXED, __HIP_MEMORY_SCOPE_AGENT);
      }
    }
  } else {
    // ---------------- stage 2: L2 ----------------
    float4 w[35];
    float bias;
    {
      const int row = (tid < 192) ? tid : 0;
      const float4* wr = (const float4*)(W2R + row * 140);
      #pragma unroll
      for (int i = 0; i < 35; ++i) w[i] = wr[i];
      bias = b2f[row];
    }
    for (int i = tid; i < 140; i += 384) xh[i] = 0.f;
    __syncthreads();
    const float4* xv = (const float4*)xh;
    const float* hbr = h1buf + (size_t)b * TT * 80;
    const unsigned int* fr = f1 + b * TT;
    float* outp = dout + (size_t)b * TT * 64;
    long g = 0;
    for (int t = 0; t < TT; ++t) {
      if (tid == 0) {
        while (__hip_atomic_load(&fr[t], __ATOMIC_RELAXED, __HIP_MEMORY_SCOPE_AGENT) != 1u) {
          __builtin_amdgcn_s_sleep(1);
          if (++g > (1L << 23)) break;
        }
        asm volatile("" ::: "memory");
      }
      __syncthreads();
      if (tid < 38) {                                // h1[t]: 76 floats = 38 x 8B
        unsigned long long v = __hip_atomic_load(
            (const unsigned long long*)(hbr + (size_t)t * 80) + tid,
            __ATOMIC_RELAXED, __HIP_MEMORY_SCOPE_AGENT);
        union { unsigned long long u; float2 f; } cv; cv.u = v;
        ((float2*)xh)[tid] = cv.f;
      }
      __syncthreads();
      if (tid < 192) {
        float a0 = 0, a1 = 0, a2 = 0, a3 = 0;
        #pragma unroll
        for (int i = 0; i < 35; ++i) {
          float4 h = xv[i];
          a0 = fmaf(w[i].x, h.x, a0); a1 = fmaf(w[i].y, h.y, a1);
          a2 = fmaf(w[i].z, h.z, a2); a3 = fmaf(w[i].w, h.w, a3);
        }
        pre[tid] = bias + ((a0 + a1) + (a2 + a3));
      }
      __syncthreads();
      if (tid < 64) {
        float h = cfc_combine(pre[tid], pre[64 + tid], pre[128 + tid]);
        xh[76 + tid] = h;
        outp[t * 64 + tid] = h;
        if (t == TT - 1) st[192 + tid] = h;
      }
      __syncthreads();
    }
  }
}

// ---------------------------------------------------------------------------
extern "C" void kernel_launch(void* const* d_in, const int* in_sizes, int n_in,
                              void* d_out, int out_size, void* d_ws, size_t ws_size,
                              hipStream_t stream) {
  (void)in_sizes; (void)n_in; (void)out_size; (void)ws_size;
  Ptrs P;
  for (int i = 0; i < 34; ++i) P.p[i] = (const float*)d_in[i];

  float* ws = (float*)d_ws;
  // layout (float indices); h0buf aliases feats (feats dead after proj_kernel)
  float* feats = ws;                        // 2097152
  float* proj0 = ws + 2097152;              // 5701632 -> 7798784
  float* fcwT  = ws + 7798784;              // 16384   -> 7815168
  float* M0T   = ws + 7815168;              // 44544   -> 7859712
  float* W0R   = ws + 7859712;              // 40368   -> 7900080
  float* W1R   = ws + 7900080;              // 43776   -> 7943856
  float* W2R   = ws + 7943856;              // 26880   -> 7970736
  float* b1f   = ws + 7970736;              // 228     -> 7970964
  float* b2f   = ws + 7970964;              // 192     -> 7971156
  float* h0buf = feats;                     // 32*512*128 = 2097152 (alias)
  float* h1buf = ws + 7971156;              // 32*512*80 = 1310720 -> 9281876
  unsigned int* f0 = (unsigned int*)(ws + 9281876);   // 16384 -> 9298260
  unsigned int* f1 = (unsigned int*)(ws + 9298260);   // 16384 -> 9314644 (37.3 MB)

  prep_kernel<<<(PREP_TOTAL + 255) / 256, 256, 0, stream>>>(P, fcwT, M0T, W0R, W1R,
                                                            W2R, b1f, b2f, f0);
  encoder_kernel<<<BB * TT, 128, 0, stream>>>(P.p[0], P.p[1], P.p[2], P.p[3],
                                              P.p[4], fcwT, P.p[6], feats);
  proj_kernel<<<(BB * TT) / 32, 384, 0, stream>>>(feats, M0T, P.p[12], P.p[13],
                                                  P.p[14], P.p[15], proj0);
  recurrent_kernel<<<BB * 3, 384, 0, stream>>>(proj0, W0R, W1R, W2R, b1f, b2f,
                                               h0buf, h1buf, f0, f1, (float*)d_out);
}

// Round 8
// 1519.353 us; speedup vs baseline: 2.5173x; 1.1851x over previous
//
#include <hip/hip_runtime.h>
#include <hip/hip_bf16.h>

// ---------------------------------------------------------------------------
// LiquidPerceptionUnit: CNN encoder (per-timestep) + 3-layer WiredCfC scan.
// B=32, T=512, L=256, FEAT=128; layers (fin,hid): (128,116),(116,76),(76,64)
//
//   K0 prep   : fold mask into w1/w2, fold wa+wb, row-major weight rows.
//   K1 encode : one block per sample -> feats[16384][128]
//   K2 proj   : feats @ L0-input-weights (+biases) -> proj0[16384][348]
//   K3 zero   : zero h0buf (aliases feats, dead after proj) + h1buf
//   K4 recur  : 96 blocks = 32 batches x 3 layer-stages, pipelined over t.
//               Weights PINNED in VGPRs (asm pin defeats rematerialization).
//               Handoff: payload-as-flag (h+2 in [1,3); poison/zero invalid),
//               prefetched one iteration ahead; raw s_barrier (no vmcnt
//               drain) so stores/prefetches stay in flight.
//               NOTE: handoff rows addressed as ULL elements — row strides
//               H0_ULL=64 (128 floats), H1_ULL=40 (80 floats). Round-6 bug
//               was using float-strides (16/10) here.
// ---------------------------------------------------------------------------

#define BB 32
#define TT 512
#define H0_ULL 64                 // h0 row: 128 floats = 64 x 8B
#define H1_ULL 40                 // h1 row:  80 floats = 40 x 8B

struct Ptrs { const float* p[34]; };

__device__ __forceinline__ float wv(const float* w1, const float* w2,
                                    const float* wa, const float* wb,
                                    const float* msk, int m, int o, int col, int cat) {
  int idx = o * cat + col;
  if (m == 0) return w1[idx] * msk[idx];
  if (m == 1) return w2[idx] * msk[idx];
  return wa[idx] + wb[idx];
}

// prep regions (floats)
#define SZ_FCWT  16384            // [32][128][4]  fc_w transposed+packed
#define SZ_M0T   44544            // [32][348][4]  L0 input-proj weights (k-major)
#define SZ_W0R   40368            // [348][116]    L0 recurrent rows (row-major)
#define SZ_W1R   43776            // [228][192]    L1 rows
#define SZ_W2R   26880            // [192][140]    L2 rows
#define SZ_B1    228
#define SZ_B2    192
#define PREP_TOTAL (SZ_FCWT + SZ_M0T + SZ_W0R + SZ_W1R + SZ_W2R + SZ_B1 + SZ_B2)

__global__ void prep_kernel(Ptrs P, float* __restrict__ fcwTp, float* __restrict__ M0Tp,
                            float* __restrict__ W0R, float* __restrict__ W1R,
                            float* __restrict__ W2R, float* __restrict__ b1f,
                            float* __restrict__ b2f) {
  int i = blockIdx.x * blockDim.x + threadIdx.x;
  if (i < SZ_FCWT) {                    // fc_w: [kc][f][q] = fc_w[f][kc*4+q]
    int kc = i >> 9, r = i & 511, f = r >> 2, q = r & 3;
    fcwTp[i] = P.p[5][f * 128 + (kc * 4 + q)];
    return;
  }
  i -= SZ_FCWT;
  if (i < SZ_M0T) {                     // L0 input part, k-major (cols 0..127 of cat 244)
    int kc = i / 1392, r = i % 1392, c = r >> 2, q = r & 3;
    int k = kc * 4 + q, m = c / 116, o = c % 116;
    M0Tp[i] = wv(P.p[8], P.p[9], P.p[10], P.p[11], P.p[7], m, o, k, 244);
    return;
  }
  i -= SZ_M0T;
  if (i < SZ_W0R) {                     // L0 recurrent rows: [c][k], col=128+k
    int c = i / 116, k = i % 116;
    W0R[i] = wv(P.p[8], P.p[9], P.p[10], P.p[11], P.p[7], c / 116, c % 116, 128 + k, 244);
    return;
  }
  i -= SZ_W0R;
  if (i < SZ_W1R) {                     // L1 rows: [c][k], cat=192
    int c = i / 192, k = i % 192;
    W1R[i] = wv(P.p[17], P.p[18], P.p[19], P.p[20], P.p[16], c / 76, c % 76, k, 192);
    return;
  }
  i -= SZ_W1R;
  if (i < SZ_W2R) {                     // L2 rows: [c][k], cat=140
    int c = i / 140, k = i % 140;
    W2R[i] = wv(P.p[26], P.p[27], P.p[28], P.p[29], P.p[25], c / 64, c % 64, k, 140);
    return;
  }
  i -= SZ_W2R;
  if (i < SZ_B1) {
    int m = i / 76, o = i % 76;
    b1f[i] = (m == 0) ? P.p[21][o] : (m == 1) ? P.p[22][o] : (P.p[23][o] + P.p[24][o]);
    return;
  }
  i -= SZ_B1;
  if (i < SZ_B2) {
    int m = i / 64, o = i % 64;
    b2f[i] = (m == 0) ? P.p[30][o] : (m == 1) ? P.p[31][o] : (P.p[32][o] + P.p[33][o]);
    return;
  }
}

// ---------------------------------------------------------------------------
// Encoder: one block (128 threads) per sample.
__global__ __launch_bounds__(128) void encoder_kernel(
    const float* __restrict__ x, const float* __restrict__ c1w,
    const float* __restrict__ c1b, const float* __restrict__ c2w,
    const float* __restrict__ c2b, const float* __restrict__ fcwTp,
    const float* __restrict__ fcb, float* __restrict__ feats) {
  __shared__ __align__(16) float xsh[258];
  __shared__ float pooled[128];                 // [p(8)][c(16)]
  __shared__ __align__(16) float vflat[128];    // [c(32)*4 + p4]
  const int n = blockIdx.x, tid = threadIdx.x;
  const float* xr = x + n * 256;
  xsh[1 + tid] = xr[tid];
  xsh[129 + tid] = xr[128 + tid];
  if (tid == 0) { xsh[0] = 0.f; xsh[257] = 0.f; }
  __syncthreads();
  {                                             // conv1 + relu + avgpool(32)
    int c = tid & 15, p = tid >> 4;
    float w0 = c1w[c * 3], w1 = c1w[c * 3 + 1], w2 = c1w[c * 3 + 2], b = c1b[c];
    float s = 0.f;
    int base = p * 32;
    #pragma unroll 8
    for (int j = 0; j < 32; ++j) {
      float v = b + w0 * xsh[base + j] + w1 * xsh[base + j + 1] + w2 * xsh[base + j + 2];
      s += fmaxf(v, 0.f);
    }
    pooled[p * 16 + c] = s * (1.f / 32.f);
  }
  __syncthreads();
  {                                             // conv2 + relu + avgpool(2)
    int c = tid & 31, p4 = tid >> 5;
    float s = 0.f;
    for (int pp = 0; pp < 2; ++pp) {
      int p = p4 * 2 + pp;
      float v = c2b[c];
      #pragma unroll
      for (int ci = 0; ci < 16; ++ci) {
        #pragma unroll
        for (int j = 0; j < 3; ++j) {
          int q = p + j - 1;
          float pv = (q >= 0 && q < 8) ? pooled[q * 16 + ci] : 0.f;
          v = fmaf(c2w[(c * 16 + ci) * 3 + j], pv, v);
        }
      }
      s += fmaxf(v, 0.f);
    }
    vflat[c * 4 + p4] = s * 0.5f;
  }
  __syncthreads();
  {                                             // FC 128x128
    const float4* W = (const float4*)fcwTp;
    const float4* vv = (const float4*)vflat;
    float a0 = 0, a1 = 0, a2 = 0, a3 = 0;
    #pragma unroll 8
    for (int kc = 0; kc < 32; ++kc) {
      float4 w = W[kc * 128 + tid];
      float4 h = vv[kc];
      a0 = fmaf(w.x, h.x, a0); a1 = fmaf(w.y, h.y, a1);
      a2 = fmaf(w.z, h.z, a2); a3 = fmaf(w.w, h.w, a3);
    }
    feats[n * 128 + tid] = fcb[tid] + ((a0 + a1) + (a2 + a3));
  }
}

// ---------------------------------------------------------------------------
// L0 input projection: thread c computes output c for 32 samples.
__global__ __launch_bounds__(384) void proj_kernel(
    const float* __restrict__ feats, const float* __restrict__ M0Tp,
    const float* __restrict__ b01, const float* __restrict__ b02,
    const float* __restrict__ b0a, const float* __restrict__ b0b,
    float* __restrict__ proj0) {
  __shared__ __align__(16) float fl[32 * 128];
  const int tid = threadIdx.x;
  const int n0 = blockIdx.x * 32;
  const float4* src = (const float4*)(feats + (size_t)n0 * 128);
  float4* dst4 = (float4*)fl;
  for (int i = tid; i < 1024; i += 384) dst4[i] = src[i];
  __syncthreads();
  if (tid < 348) {
    const int c = tid, m = c / 116, o = c % 116;
    const float bias = (m == 0) ? b01[o] : (m == 1) ? b02[o] : (b0a[o] + b0b[o]);
    float acc[32];
    #pragma unroll
    for (int s = 0; s < 32; ++s) acc[s] = bias;
    const float4* W4 = (const float4*)M0Tp;
    const float4* flv = (const float4*)fl;
    for (int kc = 0; kc < 32; ++kc) {
      const float4 w = W4[kc * 348 + c];
      #pragma unroll
      for (int s = 0; s < 32; ++s) {
        float4 h = flv[s * 32 + kc];
        acc[s] = fmaf(w.x, h.x, fmaf(w.y, h.y, fmaf(w.z, h.z, fmaf(w.w, h.w, acc[s]))));
      }
    }
    float* op = proj0 + (size_t)n0 * 348 + c;
    #pragma unroll
    for (int s = 0; s < 32; ++s) op[s * 348] = acc[s];
  }
}

// ---------------------------------------------------------------------------
// Zero the handoff buffers (h0buf aliases feats which is dead after proj).
__global__ __launch_bounds__(256) void zero_kernel(float4* __restrict__ a, int n4a,
                                                   float4* __restrict__ b, int n4b) {
  const int stride = gridDim.x * blockDim.x;
  const float4 z = make_float4(0.f, 0.f, 0.f, 0.f);
  for (int j = blockIdx.x * blockDim.x + threadIdx.x; j < n4a; j += stride) a[j] = z;
  for (int j = blockIdx.x * blockDim.x + threadIdx.x; j < n4b; j += stride) b[j] = z;
}

// ---------------------------------------------------------------------------
__device__ __forceinline__ float fast_sig(float x) {
  x = fminf(fmaxf(x, -30.f), 30.f);
  return 1.f / (1.f + __expf(-x));
}
__device__ __forceinline__ float fast_tanh(float x) {
  x = fminf(fmaxf(x, -15.f), 15.f);
  float e = __expf(2.f * x);
  return (e - 1.f) / (e + 1.f);
}
__device__ __forceinline__ float cfc_combine(float p1, float p2, float pt) {
  float ti = fast_sig(pt);
  float f1 = fast_tanh(p1), f2 = fast_tanh(p2);
  return f1 + ti * (f2 - f1);
}

// raw barrier: LDS drain only — no vmcnt(0), stores/prefetches stay in flight
__device__ __forceinline__ void block_bar() {
  __builtin_amdgcn_sched_barrier(0);
  asm volatile("s_waitcnt lgkmcnt(0)" ::: "memory");
  __builtin_amdgcn_s_barrier();
  __builtin_amdgcn_sched_barrier(0);
}

__device__ __forceinline__ float2 decode2(unsigned long long u) {
  union { unsigned long long u; float2 f; } c; c.u = u; return c.f;
}
__device__ __forceinline__ bool valid2(float2 v) { return (v.x >= 1.f) && (v.y >= 1.f); }

// Deadman counter g accumulates across the WHOLE scan (by reference):
// total spin per block is bounded -> a logic bug fails validation, never hangs.
__device__ __forceinline__ float2 wait_payload(const unsigned long long* p,
                                               unsigned long long first, long& g) {
  float2 v = decode2(first);
  while (!valid2(v)) {
    __builtin_amdgcn_s_sleep(2);
    v = decode2(__hip_atomic_load(p, __ATOMIC_RELAXED, __HIP_MEMORY_SCOPE_AGENT));
    if (++g > (1L << 22)) break;
  }
  return v;
}

#define PIN4(wreg) asm volatile("" : "+v"(wreg.x), "+v"(wreg.y), "+v"(wreg.z), "+v"(wreg.w))

// Pipelined recurrent scan: grid = 32 batches x 3 stages.
__global__ __launch_bounds__(384, 2) void recurrent_kernel(
    const float* __restrict__ proj0, const float* __restrict__ W0R,
    const float* __restrict__ W1R, const float* __restrict__ W2R,
    const float* __restrict__ b1f, const float* __restrict__ b2f,
    float* __restrict__ h0buf, float* __restrict__ h1buf,
    float* __restrict__ dout) {
  __shared__ __align__(16) float xh[192];
  __shared__ float pre[348];
  const int tid = threadIdx.x;
  const int b = blockIdx.x / 3;
  const int role = blockIdx.x % 3;
  float* st = dout + BB * TT * 64 + b * 256;

  if (role == 0) {
    // ---------------- stage 0: L0 (self-recurrent) ----------------
    float4 w[29];
    {
      const int row = (tid < 348) ? tid : 0;
      const float4* wr = (const float4*)(W0R + row * 116);
      #pragma unroll
      for (int i = 0; i < 29; ++i) { w[i] = wr[i]; }
      #pragma unroll
      for (int i = 0; i < 29; ++i) { PIN4(w[i]); }
    }
    if (tid < 116) xh[tid] = 0.f;
    const float* pr = proj0 + (size_t)b * TT * 348;
    float* hb = h0buf + (size_t)b * TT * 128;
    float pv = 0.f, pw = 0.f, px = 0.f;
    if (tid < 348) { pv = pr[tid]; pw = pr[348 + tid]; px = pr[696 + tid]; }
    block_bar();
    const float4* xv = (const float4*)xh;
    for (int t = 0; t < TT; ++t) {
      if (tid < 348) {
        float a0 = 0, a1 = 0, a2 = 0, a3 = 0;
        #pragma unroll
        for (int i = 0; i < 29; ++i) {
          float4 h = xv[i];
          a0 = fmaf(w[i].x, h.x, a0); a1 = fmaf(w[i].y, h.y, a1);
          a2 = fmaf(w[i].z, h.z, a2); a3 = fmaf(w[i].w, h.w, a3);
        }
        pre[tid] = pv + ((a0 + a1) + (a2 + a3));
      }
      block_bar();                               // barA
      if (tid < 116) {
        float h = cfc_combine(pre[tid], pre[116 + tid], pre[232 + tid]);
        xh[tid] = h;
        __hip_atomic_store(&hb[(size_t)t * 128 + tid], h + 2.0f,
                           __ATOMIC_RELAXED, __HIP_MEMORY_SCOPE_AGENT);
        if (t == TT - 1) st[tid] = h;
      }
      pv = pw; pw = px;
      if (tid < 348 && t + 3 < TT) px = pr[(size_t)(t + 3) * 348 + tid];
      block_bar();                               // barB
    }
  } else if (role == 1) {
    // ---------------- stage 1: L1 ----------------
    float4 w[48];
    float bias;
    {
      const int row = (tid < 228) ? tid : 0;
      const float4* wr = (const float4*)(W1R + row * 192);
      #pragma unroll
      for (int i = 0; i < 48; ++i) { w[i] = wr[i]; }
      #pragma unroll
      for (int i = 0; i < 48; ++i) { PIN4(w[i]); }
      bias = b1f[row];
    }
    if (tid >= 116 && tid < 192) xh[tid] = 0.f;
    const unsigned long long* pl = (const unsigned long long*)(h0buf + (size_t)b * TT * 128);
    float* hbw = h1buf + (size_t)b * TT * 80;
    unsigned long long nxt = 0;
    long g = 0;
    if (tid < 58) {                              // prologue: h0(0) + prefetch h0(1)
      unsigned long long c0 = __hip_atomic_load(pl + tid, __ATOMIC_RELAXED,
                                                __HIP_MEMORY_SCOPE_AGENT);
      float2 v = wait_payload(pl + tid, c0, g);
      ((float2*)xh)[tid] = make_float2(v.x - 2.f, v.y - 2.f);
      nxt = __hip_atomic_load(pl + H0_ULL + tid, __ATOMIC_RELAXED,
                              __HIP_MEMORY_SCOPE_AGENT);
    }
    block_bar();
    const float4* xv = (const float4*)xh;
    for (int t = 0; t < TT; ++t) {
      if (tid < 228) {
        float a0 = 0, a1 = 0, a2 = 0, a3 = 0;
        #pragma unroll
        for (int i = 0; i < 48; ++i) {
          float4 h = xv[i];
          a0 = fmaf(w[i].x, h.x, a0); a1 = fmaf(w[i].y, h.y, a1);
          a2 = fmaf(w[i].z, h.z, a2); a3 = fmaf(w[i].w, h.w, a3);
        }
        pre[tid] = bias + ((a0 + a1) + (a2 + a3));
      }
      block_bar();                               // barA
      if (tid < 76) {
        float h = cfc_combine(pre[tid], pre[76 + tid], pre[152 + tid]);
        xh[116 + tid] = h;
        __hip_atomic_store(&hbw[(size_t)t * 80 + tid], h + 2.0f,
                           __ATOMIC_RELAXED, __HIP_MEMORY_SCOPE_AGENT);
        if (t == TT - 1) st[116 + tid] = h;
      }
      if (tid < 58 && t + 1 < TT) {              // validate prefetched h0(t+1)
        float2 v = decode2(nxt);
        if (!valid2(v))
          v = wait_payload(pl + (size_t)(t + 1) * H0_ULL + tid, nxt, g);
        ((float2*)xh)[tid] = make_float2(v.x - 2.f, v.y - 2.f);
        if (t + 2 < TT)
          nxt = __hip_atomic_load(pl + (size_t)(t + 2) * H0_ULL + tid,
                                  __ATOMIC_RELAXED, __HIP_MEMORY_SCOPE_AGENT);
      }
      block_bar();                               // barB
    }
  } else {
    // ---------------- stage 2: L2 ----------------
    float4 w[35];
    float bias;
    {
      const int row = (tid < 192) ? tid : 0;
      const float4* wr = (const float4*)(W2R + row * 140);
      #pragma unroll
      for (int i = 0; i < 35; ++i) { w[i] = wr[i]; }
      #pragma unroll
      for (int i = 0; i < 35; ++i) { PIN4(w[i]); }
      bias = b2f[row];
    }
    if (tid >= 76 && tid < 140) xh[tid] = 0.f;
    const unsigned long long* pl = (const unsigned long long*)(h1buf + (size_t)b * TT * 80);
    float* outp = dout + (size_t)b * TT * 64;
    unsigned long long nxt = 0;
    long g = 0;
    if (tid < 38) {                              // prologue: h1(0) + prefetch h1(1)
      unsigned long long c0 = __hip_atomic_load(pl + tid, __ATOMIC_RELAXED,
                                                __HIP_MEMORY_SCOPE_AGENT);
      float2 v = wait_payload(pl + tid, c0, g);
      ((float2*)xh)[tid] = make_float2(v.x - 2.f, v.y - 2.f);
      nxt = __hip_atomic_load(pl + H1_ULL + tid, __ATOMIC_RELAXED,
                              __HIP_MEMORY_SCOPE_AGENT);
    }
    block_bar();
    const float4* xv = (const float4*)xh;
    for (int t = 0; t < TT; ++t) {
      if (tid < 192) {
        float a0 = 0, a1 = 0, a2 = 0, a3 = 0;
        #pragma unroll
        for (int i = 0; i < 35; ++i) {
          float4 h = xv[i];
          a0 = fmaf(w[i].x, h.x, a0); a1 = fmaf(w[i].y, h.y, a1);
          a2 = fmaf(w[i].z, h.z, a2); a3 = fmaf(w[i].w, h.w, a3);
        }
        pre[tid] = bias + ((a0 + a1) + (a2 + a3));
      }
      block_bar();                               // barA
      if (tid < 64) {
        float h = cfc_combine(pre[tid], pre[64 + tid], pre[128 + tid]);
        xh[76 + tid] = h;
        outp[(size_t)t * 64 + tid] = h;
        if (t == TT - 1) st[192 + tid] = h;
      }
      if (tid < 38 && t + 1 < TT) {              // validate prefetched h1(t+1)
        float2 v = decode2(nxt);
        if (!valid2(v))
          v = wait_payload(pl + (size_t)(t + 1) * H1_ULL + tid, nxt, g);
        ((float2*)xh)[tid] = make_float2(v.x - 2.f, v.y - 2.f);
        if (t + 2 < TT)
          nxt = __hip_atomic_load(pl + (size_t)(t + 2) * H1_ULL + tid,
                                  __ATOMIC_RELAXED, __HIP_MEMORY_SCOPE_AGENT);
      }
      block_bar();                               // barB
    }
  }
}

// ---------------------------------------------------------------------------
extern "C" void kernel_launch(void* const* d_in, const int* in_sizes, int n_in,
                              void* d_out, int out_size, void* d_ws, size_t ws_size,
                              hipStream_t stream) {
  (void)in_sizes; (void)n_in; (void)out_size; (void)ws_size;
  Ptrs P;
  for (int i = 0; i < 34; ++i) P.p[i] = (const float*)d_in[i];

  float* ws = (float*)d_ws;
  float* feats = ws;                        // 2097152 (reused as h0buf after proj)
  float* proj0 = ws + 2097152;              // 5701632 -> 7798784
  float* fcwT  = ws + 7798784;              // 16384   -> 7815168
  float* M0T   = ws + 7815168;              // 44544   -> 7859712
  float* W0R   = ws + 7859712;              // 40368   -> 7900080
  float* W1R   = ws + 7900080;              // 43776   -> 7943856
  float* W2R   = ws + 7943856;              // 26880   -> 7970736
  float* b1f   = ws + 7970736;              // 228     -> 7970964
  float* b2f   = ws + 7970964;              // 192     -> 7971156
  float* h0buf = feats;                     // 32*512*128 (alias; zeroed post-proj)
  float* h1buf = ws + 7971156;              // 32*512*80 -> 9281876 floats (37.1 MB)

  prep_kernel<<<(PREP_TOTAL + 255) / 256, 256, 0, stream>>>(P, fcwT, M0T, W0R, W1R,
                                                            W2R, b1f, b2f);
  encoder_kernel<<<BB * TT, 128, 0, stream>>>(P.p[0], P.p[1], P.p[2], P.p[3],
                                              P.p[4], fcwT, P.p[6], feats);
  proj_kernel<<<(BB * TT) / 32, 384, 0, stream>>>(feats, M0T, P.p[12], P.p[13],
                                                  P.p[14], P.p[15], proj0);
  zero_kernel<<<1024, 256, 0, stream>>>((float4*)h0buf, 2097152 / 4,
                                        (float4*)h1buf, 1310720 / 4);
  recurrent_kernel<<<BB * 3, 384, 0, stream>>>(proj0, W0R, W1R, W2R, b1f, b2f,
                                               h0buf, h1buf, (float*)d_out);
}

// Round 10
// 1151.366 us; speedup vs baseline: 3.3218x; 1.3196x over previous
//
#include <hip/hip_runtime.h>
#include <hip/hip_bf16.h>

// ---------------------------------------------------------------------------
// LiquidPerceptionUnit: CNN encoder (per-timestep) + 3-layer WiredCfC scan.
// B=32, T=512, L=256, FEAT=128; layers (fin,hid): (128,116),(116,76),(76,64)
//
//   K4 recur  : 96 blocks = 32 batches x 3 layer-stages, 512 threads each.
//               Weights register-resident BY CONSTRUCTION: split-K across
//               wave-aligned chunks caps per-thread weights at 29 float4
//               (116 VGPR) worst-case; launch_bounds(512,1) lifts the VGPR
//               cap to 512 so the allocator has no reason to spill (round-8
//               failure: VGPR=128 + scratch streaming = 5300 cy/step).
//               Handoff: payload-as-flag + LAG=8 slack so prefetched rows
//               arrive valid; polls are rare fallback only.
// ---------------------------------------------------------------------------

#define BB 32
#define TT 512
#define H0_ULL 64                 // h0 row: 128 floats = 64 x 8B
#define H1_ULL 40                 // h1 row:  80 floats = 40 x 8B
#define LAG 8                     // pipeline slack (steps) between stages

struct Ptrs { const float* p[34]; };

__device__ __forceinline__ float wv(const float* w1, const float* w2,
                                    const float* wa, const float* wb,
                                    const float* msk, int m, int o, int col, int cat) {
  int idx = o * cat + col;
  if (m == 0) return w1[idx] * msk[idx];
  if (m == 1) return w2[idx] * msk[idx];
  return wa[idx] + wb[idx];
}

// prep regions (floats)
#define SZ_FCWT  16384            // [32][128][4]  fc_w transposed+packed
#define SZ_M0T   44544            // [32][348][4]  L0 input-proj weights (k-major)
#define SZ_W0R   40368            // [348][116]    L0 recurrent rows (row-major)
#define SZ_W1R   43776            // [228][192]    L1 rows
#define SZ_W2R   26880            // [192][140]    L2 rows
#define SZ_B1    228
#define SZ_B2    192
#define PREP_TOTAL (SZ_FCWT + SZ_M0T + SZ_W0R + SZ_W1R + SZ_W2R + SZ_B1 + SZ_B2)

__global__ void prep_kernel(Ptrs P, float* __restrict__ fcwTp, float* __restrict__ M0Tp,
                            float* __restrict__ W0R, float* __restrict__ W1R,
                            float* __restrict__ W2R, float* __restrict__ b1f,
                            float* __restrict__ b2f) {
  int i = blockIdx.x * blockDim.x + threadIdx.x;
  if (i < SZ_FCWT) {                    // fc_w: [kc][f][q] = fc_w[f][kc*4+q]
    int kc = i >> 9, r = i & 511, f = r >> 2, q = r & 3;
    fcwTp[i] = P.p[5][f * 128 + (kc * 4 + q)];
    return;
  }
  i -= SZ_FCWT;
  if (i < SZ_M0T) {                     // L0 input part, k-major (cols 0..127 of cat 244)
    int kc = i / 1392, r = i % 1392, c = r >> 2, q = r & 3;
    int k = kc * 4 + q, m = c / 116, o = c % 116;
    M0Tp[i] = wv(P.p[8], P.p[9], P.p[10], P.p[11], P.p[7], m, o, k, 244);
    return;
  }
  i -= SZ_M0T;
  if (i < SZ_W0R) {                     // L0 recurrent rows: [c][k], col=128+k
    int c = i / 116, k = i % 116;
    W0R[i] = wv(P.p[8], P.p[9], P.p[10], P.p[11], P.p[7], c / 116, c % 116, 128 + k, 244);
    return;
  }
  i -= SZ_W0R;
  if (i < SZ_W1R) {                     // L1 rows: [c][k], cat=192
    int c = i / 192, k = i % 192;
    W1R[i] = wv(P.p[17], P.p[18], P.p[19], P.p[20], P.p[16], c / 76, c % 76, k, 192);
    return;
  }
  i -= SZ_W1R;
  if (i < SZ_W2R) {                     // L2 rows: [c][k], cat=140
    int c = i / 140, k = i % 140;
    W2R[i] = wv(P.p[26], P.p[27], P.p[28], P.p[29], P.p[25], c / 64, c % 64, k, 140);
    return;
  }
  i -= SZ_W2R;
  if (i < SZ_B1) {
    int m = i / 76, o = i % 76;
    b1f[i] = (m == 0) ? P.p[21][o] : (m == 1) ? P.p[22][o] : (P.p[23][o] + P.p[24][o]);
    return;
  }
  i -= SZ_B1;
  if (i < SZ_B2) {
    int m = i / 64, o = i % 64;
    b2f[i] = (m == 0) ? P.p[30][o] : (m == 1) ? P.p[31][o] : (P.p[32][o] + P.p[33][o]);
    return;
  }
}

// ---------------------------------------------------------------------------
// Encoder: one block (128 threads) per sample.
__global__ __launch_bounds__(128) void encoder_kernel(
    const float* __restrict__ x, const float* __restrict__ c1w,
    const float* __restrict__ c1b, const float* __restrict__ c2w,
    const float* __restrict__ c2b, const float* __restrict__ fcwTp,
    const float* __restrict__ fcb, float* __restrict__ feats) {
  __shared__ __align__(16) float xsh[258];
  __shared__ float pooled[128];                 // [p(8)][c(16)]
  __shared__ __align__(16) float vflat[128];    // [c(32)*4 + p4]
  const int n = blockIdx.x, tid = threadIdx.x;
  const float* xr = x + n * 256;
  xsh[1 + tid] = xr[tid];
  xsh[129 + tid] = xr[128 + tid];
  if (tid == 0) { xsh[0] = 0.f; xsh[257] = 0.f; }
  __syncthreads();
  {                                             // conv1 + relu + avgpool(32)
    int c = tid & 15, p = tid >> 4;
    float w0 = c1w[c * 3], w1 = c1w[c * 3 + 1], w2 = c1w[c * 3 + 2], b = c1b[c];
    float s = 0.f;
    int base = p * 32;
    #pragma unroll 8
    for (int j = 0; j < 32; ++j) {
      float v = b + w0 * xsh[base + j] + w1 * xsh[base + j + 1] + w2 * xsh[base + j + 2];
      s += fmaxf(v, 0.f);
    }
    pooled[p * 16 + c] = s * (1.f / 32.f);
  }
  __syncthreads();
  {                                             // conv2 + relu + avgpool(2)
    int c = tid & 31, p4 = tid >> 5;
    float s = 0.f;
    for (int pp = 0; pp < 2; ++pp) {
      int p = p4 * 2 + pp;
      float v = c2b[c];
      #pragma unroll
      for (int ci = 0; ci < 16; ++ci) {
        #pragma unroll
        for (int j = 0; j < 3; ++j) {
          int q = p + j - 1;
          float pv = (q >= 0 && q < 8) ? pooled[q * 16 + ci] : 0.f;
          v = fmaf(c2w[(c * 16 + ci) * 3 + j], pv, v);
        }
      }
      s += fmaxf(v, 0.f);
    }
    vflat[c * 4 + p4] = s * 0.5f;
  }
  __syncthreads();
  {                                             // FC 128x128
    const float4* W = (const float4*)fcwTp;
    const float4* vv = (const float4*)vflat;
    float a0 = 0, a1 = 0, a2 = 0, a3 = 0;
    #pragma unroll 8
    for (int kc = 0; kc < 32; ++kc) {
      float4 w = W[kc * 128 + tid];
      float4 h = vv[kc];
      a0 = fmaf(w.x, h.x, a0); a1 = fmaf(w.y, h.y, a1);
      a2 = fmaf(w.z, h.z, a2); a3 = fmaf(w.w, h.w, a3);
    }
    feats[n * 128 + tid] = fcb[tid] + ((a0 + a1) + (a2 + a3));
  }
}

// ---------------------------------------------------------------------------
// L0 input projection: thread c computes output c for 32 samples.
__global__ __launch_bounds__(384) void proj_kernel(
    const float* __restrict__ feats, const float* __restrict__ M0Tp,
    const float* __restrict__ b01, const float* __restrict__ b02,
    const float* __restrict__ b0a, const float* __restrict__ b0b,
    float* __restrict__ proj0) {
  __shared__ __align__(16) float fl[32 * 128];
  const int tid = threadIdx.x;
  const int n0 = blockIdx.x * 32;
  const float4* src = (const float4*)(feats + (size_t)n0 * 128);
  float4* dst4 = (float4*)fl;
  for (int i = tid; i < 1024; i += 384) dst4[i] = src[i];
  __syncthreads();
  if (tid < 348) {
    const int c = tid, m = c / 116, o = c % 116;
    const float bias = (m == 0) ? b01[o] : (m == 1) ? b02[o] : (b0a[o] + b0b[o]);
    float acc[32];
    #pragma unroll
    for (int s = 0; s < 32; ++s) acc[s] = bias;
    const float4* W4 = (const float4*)M0Tp;
    const float4* flv = (const float4*)fl;
    for (int kc = 0; kc < 32; ++kc) {
      const float4 w = W4[kc * 348 + c];
      #pragma unroll
      for (int s = 0; s < 32; ++s) {
        float4 h = flv[s * 32 + kc];
        acc[s] = fmaf(w.x, h.x, fmaf(w.y, h.y, fmaf(w.z, h.z, fmaf(w.w, h.w, acc[s]))));
      }
    }
    float* op = proj0 + (size_t)n0 * 348 + c;
    #pragma unroll
    for (int s = 0; s < 32; ++s) op[s * 348] = acc[s];
  }
}

// ---------------------------------------------------------------------------
// Zero the handoff buffers (h0buf aliases feats which is dead after proj).
__global__ __launch_bounds__(256) void zero_kernel(float4* __restrict__ a, int n4a,
                                                   float4* __restrict__ b, int n4b) {
  const int stride = gridDim.x * blockDim.x;
  const float4 z = make_float4(0.f, 0.f, 0.f, 0.f);
  for (int j = blockIdx.x * blockDim.x + threadIdx.x; j < n4a; j += stride) a[j] = z;
  for (int j = blockIdx.x * blockDim.x + threadIdx.x; j < n4b; j += stride) b[j] = z;
}

// ---------------------------------------------------------------------------
__device__ __forceinline__ float fast_sig(float x) {
  x = fminf(fmaxf(x, -30.f), 30.f);
  return 1.f / (1.f + __expf(-x));
}
__device__ __forceinline__ float fast_tanh(float x) {
  x = fminf(fmaxf(x, -15.f), 15.f);
  float e = __expf(2.f * x);
  return (e - 1.f) / (e + 1.f);
}
__device__ __forceinline__ float cfc_combine(float p1, float p2, float pt) {
  float ti = fast_sig(pt);
  float f1 = fast_tanh(p1), f2 = fast_tanh(p2);
  return f1 + ti * (f2 - f1);
}

// raw barrier: LDS drain only — no vmcnt(0), stores/prefetches stay in flight
__device__ __forceinline__ void block_bar() {
  __builtin_amdgcn_sched_barrier(0);
  asm volatile("s_waitcnt lgkmcnt(0)" ::: "memory");
  __builtin_amdgcn_s_barrier();
  __builtin_amdgcn_sched_barrier(0);
}

__device__ __forceinline__ float2 decode2(unsigned long long u) {
  union { unsigned long long u; float2 f; } c; c.u = u; return c.f;
}
__device__ __forceinline__ bool valid2(float2 v) { return (v.x >= 1.f) && (v.y >= 1.f); }

// Deadman counter g accumulates across the WHOLE scan (by reference):
// total spin per block is bounded -> a logic bug fails validation, never hangs.
__device__ __forceinline__ float2 wait_payload(const unsigned long long* p,
                                               unsigned long long first, long& g) {
  float2 v = decode2(first);
  while (!valid2(v)) {
    __builtin_amdgcn_s_sleep(1);
    v = decode2(__hip_atomic_load(p, __ATOMIC_RELAXED, __HIP_MEMORY_SCOPE_AGENT));
    if (++g > (1L << 22)) break;
  }
  return v;
}

#define PIN4(wreg) asm volatile("" : "+v"(wreg.x), "+v"(wreg.y), "+v"(wreg.z), "+v"(wreg.w))

// Pipelined recurrent scan: grid = 32 batches x 3 stages, 512 threads/block.
// Split-K: chunk0 = waves 0-3 (tid<256), chunk1 = waves 4-7 (tid>=256), so
// each dot loop is wave-uniform and LDS reads stay broadcast.
__global__ __launch_bounds__(512, 1) void recurrent_kernel(
    const float* __restrict__ proj0, const float* __restrict__ W0R,
    const float* __restrict__ W1R, const float* __restrict__ W2R,
    const float* __restrict__ b1f, const float* __restrict__ b2f,
    float* __restrict__ h0buf, float* __restrict__ h1buf,
    float* __restrict__ dout) {
  __shared__ __align__(16) float xh[192];
  __shared__ float pre[456];
  const int tid = threadIdx.x;
  const int b = blockIdx.x / 3;
  const int role = blockIdx.x % 3;
  float* st = dout + BB * TT * 64 + b * 256;

  if (role == 0) {
    // ---------------- stage 0: L0 (self-recurrent, K=116, no split) --------
    float4 w[29];
    {
      const int row = (tid < 348) ? tid : 0;
      const float4* wr = (const float4*)(W0R + row * 116);
      #pragma unroll
      for (int i = 0; i < 29; ++i) { w[i] = wr[i]; }
      #pragma unroll
      for (int i = 0; i < 29; ++i) { PIN4(w[i]); }
    }
    if (tid < 116) xh[tid] = 0.f;
    const float* pr = proj0 + (size_t)b * TT * 348;
    float* hb = h0buf + (size_t)b * TT * 128;
    float pv = 0.f, pw = 0.f, px = 0.f;
    if (tid < 348) { pv = pr[tid]; pw = pr[348 + tid]; px = pr[696 + tid]; }
    block_bar();
    const float4* xv = (const float4*)xh;
    for (int t = 0; t < TT; ++t) {
      if (tid < 348) {
        float a0 = 0, a1 = 0, a2 = 0, a3 = 0;
        #pragma unroll
        for (int i = 0; i < 29; ++i) {
          float4 h = xv[i];
          a0 = fmaf(w[i].x, h.x, a0); a1 = fmaf(w[i].y, h.y, a1);
          a2 = fmaf(w[i].z, h.z, a2); a3 = fmaf(w[i].w, h.w, a3);
        }
        pre[tid] = pv + ((a0 + a1) + (a2 + a3));
      }
      block_bar();                               // barA
      if (tid < 116) {
        float h = cfc_combine(pre[tid], pre[116 + tid], pre[232 + tid]);
        xh[tid] = h;
        __hip_atomic_store(&hb[(size_t)t * 128 + tid], h + 2.0f,
                           __ATOMIC_RELAXED, __HIP_MEMORY_SCOPE_AGENT);
        if (t == TT - 1) st[tid] = h;
      }
      pv = pw; pw = px;
      if (tid < 348 && t + 3 < TT) px = pr[(size_t)(t + 3) * 348 + tid];
      block_bar();                               // barB
    }
  } else if (role == 1) {
    // ---------------- stage 1: L1 (K=192, split-K 2x96) ----------------
    const int col = (tid < 256) ? tid : tid - 256;
    const int chunk = (tid < 256) ? 0 : 1;
    const bool act = (col < 228);
    float4 w[24];
    float bias;
    {
      const int off = act ? (col * 192 + chunk * 96) : 0;
      const float4* wr = (const float4*)(W1R + off);
      #pragma unroll
      for (int i = 0; i < 24; ++i) { w[i] = wr[i]; }
      #pragma unroll
      for (int i = 0; i < 24; ++i) { PIN4(w[i]); }
      bias = (act && chunk == 0) ? b1f[col] : 0.f;
    }
    if (tid >= 116 && tid < 192) xh[tid] = 0.f;
    const unsigned long long* pl = (const unsigned long long*)(h0buf + (size_t)b * TT * 128);
    float* hbw = h1buf + (size_t)b * TT * 80;
    unsigned long long nxt = 0;
    long g = 0;
    if (tid < 58) {
      // pipeline slack: wait for row LAG (perf hint; per-element checks remain)
      unsigned long long cL = __hip_atomic_load(pl + (size_t)LAG * H0_ULL + tid,
                                                __ATOMIC_RELAXED, __HIP_MEMORY_SCOPE_AGENT);
      wait_payload(pl + (size_t)LAG * H0_ULL + tid, cL, g);
      // h0(0) + prefetch h0(1)
      unsigned long long c0 = __hip_atomic_load(pl + tid, __ATOMIC_RELAXED,
                                                __HIP_MEMORY_SCOPE_AGENT);
      float2 v = wait_payload(pl + tid, c0, g);
      ((float2*)xh)[tid] = make_float2(v.x - 2.f, v.y - 2.f);
      nxt = __hip_atomic_load(pl + H0_ULL + tid, __ATOMIC_RELAXED,
                              __HIP_MEMORY_SCOPE_AGENT);
    }
    block_bar();
    const float4* xv = (const float4*)xh;
    const int xbase = chunk * 24;                // wave-uniform
    for (int t = 0; t < TT; ++t) {
      if (act) {
        float a0 = 0, a1 = 0, a2 = 0, a3 = 0;
        #pragma unroll
        for (int i = 0; i < 24; ++i) {
          float4 h = xv[xbase + i];
          a0 = fmaf(w[i].x, h.x, a0); a1 = fmaf(w[i].y, h.y, a1);
          a2 = fmaf(w[i].z, h.z, a2); a3 = fmaf(w[i].w, h.w, a3);
        }
        pre[chunk * 228 + col] = bias + ((a0 + a1) + (a2 + a3));
      }
      block_bar();                               // barA
      if (tid < 76) {
        float p1 = pre[tid] + pre[228 + tid];
        float p2 = pre[76 + tid] + pre[304 + tid];
        float pt = pre[152 + tid] + pre[380 + tid];
        float h = cfc_combine(p1, p2, pt);
        xh[116 + tid] = h;
        __hip_atomic_store(&hbw[(size_t)t * 80 + tid], h + 2.0f,
                           __ATOMIC_RELAXED, __HIP_MEMORY_SCOPE_AGENT);
        if (t == TT - 1) st[116 + tid] = h;
      }
      if (tid < 58 && t + 1 < TT) {              // validate prefetched h0(t+1)
        float2 v = decode2(nxt);
        if (!valid2(v))
          v = wait_payload(pl + (size_t)(t + 1) * H0_ULL + tid, nxt, g);
        ((float2*)xh)[tid] = make_float2(v.x - 2.f, v.y - 2.f);
        if (t + 2 < TT)
          nxt = __hip_atomic_load(pl + (size_t)(t + 2) * H0_ULL + tid,
                                  __ATOMIC_RELAXED, __HIP_MEMORY_SCOPE_AGENT);
      }
      block_bar();                               // barB
    }
  } else {
    // ---------------- stage 2: L2 (K=140, split-K 72/68) ----------------
    const int col = (tid < 256) ? tid : tid - 256;
    const int chunk = (tid < 256) ? 0 : 1;
    const bool act = (col < 192);
    float4 w[18];
    float bias;
    {
      const int off = act ? (col * 140 + chunk * 72) : 0;
      const float4* wr = (const float4*)(W2R + off);
      if (chunk == 0) {
        #pragma unroll
        for (int i = 0; i < 18; ++i) { w[i] = wr[i]; }
      } else {
        #pragma unroll
        for (int i = 0; i < 17; ++i) { w[i] = wr[i]; }
        w[17] = make_float4(0.f, 0.f, 0.f, 0.f);
      }
      #pragma unroll
      for (int i = 0; i < 18; ++i) { PIN4(w[i]); }
      bias = (act && chunk == 0) ? b2f[col] : 0.f;
    }
    if (tid >= 76 && tid < 140) xh[tid] = 0.f;
    const unsigned long long* pl = (const unsigned long long*)(h1buf + (size_t)b * TT * 80);
    float* outp = dout + (size_t)b * TT * 64;
    unsigned long long nxt = 0;
    long g = 0;
    if (tid < 38) {
      unsigned long long cL = __hip_atomic_load(pl + (size_t)LAG * H1_ULL + tid,
                                                __ATOMIC_RELAXED, __HIP_MEMORY_SCOPE_AGENT);
      wait_payload(pl + (size_t)LAG * H1_ULL + tid, cL, g);
      unsigned long long c0 = __hip_atomic_load(pl + tid, __ATOMIC_RELAXED,
                                                __HIP_MEMORY_SCOPE_AGENT);
      float2 v = wait_payload(pl + tid, c0, g);
      ((float2*)xh)[tid] = make_float2(v.x - 2.f, v.y - 2.f);
      nxt = __hip_atomic_load(pl + H1_ULL + tid, __ATOMIC_RELAXED,
                              __HIP_MEMORY_SCOPE_AGENT);
    }
    block_bar();
    const float4* xv = (const float4*)xh;
    for (int t = 0; t < TT; ++t) {
      if (act) {
        float a0 = 0, a1 = 0, a2 = 0, a3 = 0;
        if (chunk == 0) {                        // k in [0,72)
          #pragma unroll
          for (int i = 0; i < 18; ++i) {
            float4 h = xv[i];
            a0 = fmaf(w[i].x, h.x, a0); a1 = fmaf(w[i].y, h.y, a1);
            a2 = fmaf(w[i].z, h.z, a2); a3 = fmaf(w[i].w, h.w, a3);
          }
        } else {                                 // k in [72,140)
          #pragma unroll
          for (int i = 0; i < 17; ++i) {
            float4 h = xv[18 + i];
            a0 = fmaf(w[i].x, h.x, a0); a1 = fmaf(w[i].y, h.y, a1);
            a2 = fmaf(w[i].z, h.z, a2); a3 = fmaf(w[i].w, h.w, a3);
          }
        }
        pre[chunk * 192 + col] = bias + ((a0 + a1) + (a2 + a3));
      }
      block_bar();                               // barA
      if (tid < 64) {
        float p1 = pre[tid] + pre[192 + tid];
        float p2 = pre[64 + tid] + pre[256 + tid];
        float pt = pre[128 + tid] + pre[320 + tid];
        float h = cfc_combine(p1, p2, pt);
        xh[76 + tid] = h;
        outp[(size_t)t * 64 + tid] = h;
        if (t == TT - 1) st[192 + tid] = h;
      }
      if (tid < 38 && t + 1 < TT) {              // validate prefetched h1(t+1)
        float2 v = decode2(nxt);
        if (!valid2(v))
          v = wait_payload(pl + (size_t)(t + 1) * H1_ULL + tid, nxt, g);
        ((float2*)xh)[tid] = make_float2(v.x - 2.f, v.y - 2.f);
        if (t + 2 < TT)
          nxt = __hip_atomic_load(pl + (size_t)(t + 2) * H1_ULL + tid,
                                  __ATOMIC_RELAXED, __HIP_MEMORY_SCOPE_AGENT);
      }
      block_bar();                               // barB
    }
  }
}

// ---------------------------------------------------------------------------
extern "C" void kernel_launch(void* const* d_in, const int* in_sizes, int n_in,
                              void* d_out, int out_size, void* d_ws, size_t ws_size,
                              hipStream_t stream) {
  (void)in_sizes; (void)n_in; (void)out_size; (void)ws_size;
  Ptrs P;
  for (int i = 0; i < 34; ++i) P.p[i] = (const float*)d_in[i];

  float* ws = (float*)d_ws;
  float* feats = ws;                        // 2097152 (reused as h0buf after proj)
  float* proj0 = ws + 2097152;              // 5701632 -> 7798784
  float* fcwT  = ws + 7798784;              // 16384   -> 7815168
  float* M0T   = ws + 7815168;              // 44544   -> 7859712
  float* W0R   = ws + 7859712;              // 40368   -> 7900080
  float* W1R   = ws + 7900080;              // 43776   -> 7943856
  float* W2R   = ws + 7943856;              // 26880   -> 7970736
  float* b1f   = ws + 7970736;              // 228     -> 7970964
  float* b2f   = ws + 7970964;              // 192     -> 7971156
  float* h0buf = feats;                     // 32*512*128 (alias; zeroed post-proj)
  float* h1buf = ws + 7971156;              // 32*512*80 -> 9281876 floats (37.1 MB)

  prep_kernel<<<(PREP_TOTAL + 255) / 256, 256, 0, stream>>>(P, fcwT, M0T, W0R, W1R,
                                                            W2R, b1f, b2f);
  encoder_kernel<<<BB * TT, 128, 0, stream>>>(P.p[0], P.p[1], P.p[2], P.p[3],
                                              P.p[4], fcwT, P.p[6], feats);
  proj_kernel<<<(BB * TT) / 32, 384, 0, stream>>>(feats, M0T, P.p[12], P.p[13],
                                                  P.p[14], P.p[15], proj0);
  zero_kernel<<<1024, 256, 0, stream>>>((float4*)h0buf, 2097152 / 4,
                                        (float4*)h1buf, 1310720 / 4);
  recurrent_kernel<<<BB * 3, 512, 0, stream>>>(proj0, W0R, W1R, W2R, b1f, b2f,
                                               h0buf, h1buf, (float*)d_out);
}